// Round 5
// baseline (267.770 us; speedup 1.0000x reference)
//
#include <hip/hip_runtime.h>

namespace {

constexpr int B = 2, S = 1024, D = 1024, H = 16, DH = 64;
constexpr int M = B * S;  // 2048 rows
constexpr float EPS = 1e-5f;

using bf16x8 = __attribute__((ext_vector_type(8))) short;  // MFMA A/B frag, K=32 (4 VGPRs)
using bf16x4 = __attribute__((ext_vector_type(4))) short;  // MFMA A/B frag, K=16 (2 VGPRs)
using f32x4  = __attribute__((ext_vector_type(4))) float;  // MFMA C/D frag

typedef const __attribute__((address_space(1))) void* gptr_t;
typedef __attribute__((address_space(3))) void* lptr_t;

__device__ __forceinline__ unsigned short f2bf(float f) {
    union { float f; unsigned u; } v{f};
    unsigned r = v.u + 0x7fffu + ((v.u >> 16) & 1u);  // RNE
    return (unsigned short)(r >> 16);
}

__device__ __forceinline__ float bflo(unsigned u) {
    union { unsigned u; float f; } v{u << 16}; return v.f;
}
__device__ __forceinline__ float bfhi(unsigned u) {
    union { unsigned u; float f; } v{u & 0xffff0000u}; return v.f;
}

__device__ __forceinline__ float wave_sum(float v) {
#pragma unroll
    for (int off = 32; off > 0; off >>= 1) v += __shfl_down(v, off, 64);
    return v;
}

// ------- Kernel 0+1 fused: W fp32->bf16 (blocks 0..3071) | LN0 (blocks 3072..5119) -------
__global__ __launch_bounds__(256) void pre_kernel(
    const float* __restrict__ Wq, const float* __restrict__ Wk,
    const float* __restrict__ Wv, unsigned short* __restrict__ Wb,
    const float* __restrict__ x, const float* __restrict__ g,
    const float* __restrict__ bt, float* __restrict__ y,
    unsigned short* __restrict__ yb)
{
    const int bx = blockIdx.x;
    const int t = threadIdx.x;
    if (bx < 3072) {
        const int z = bx >> 10;
        const float* src = (z == 0) ? Wq : (z == 1) ? Wk : Wv;
        const size_t i = ((size_t)(bx & 1023) * 256 + t) * 4;
        float4 f = *reinterpret_cast<const float4*>(src + i);
        ushort4 h;
        h.x = f2bf(f.x); h.y = f2bf(f.y); h.z = f2bf(f.z); h.w = f2bf(f.w);
        *reinterpret_cast<ushort4*>(Wb + (size_t)z * D * D + i) = h;
        return;
    }
    __shared__ float sm[8];
    __shared__ float stats[2];
    const int row = bx - 3072;
    const float4 v = reinterpret_cast<const float4*>(x + (size_t)row * D)[t];
    float s  = v.x + v.y + v.z + v.w;
    float ss = v.x*v.x + v.y*v.y + v.z*v.z + v.w*v.w;
    s = wave_sum(s); ss = wave_sum(ss);
    const int lane = t & 63, wid = t >> 6;
    if (lane == 0) { sm[wid] = s; sm[4 + wid] = ss; }
    __syncthreads();
    if (t == 0) {
        float S1 = sm[0] + sm[1] + sm[2] + sm[3];
        float S2 = sm[4] + sm[5] + sm[6] + sm[7];
        float m  = S1 * (1.0f / D);
        float var = S2 * (1.0f / D) - m * m;
        stats[0] = m; stats[1] = rsqrtf(var + EPS);
    }
    __syncthreads();
    const float m = stats[0], r = stats[1];
    const float4 gv = reinterpret_cast<const float4*>(g)[t];
    const float4 bv = reinterpret_cast<const float4*>(bt)[t];
    float4 o;
    o.x = (v.x - m) * r * gv.x + bv.x;
    o.y = (v.y - m) * r * gv.y + bv.y;
    o.z = (v.z - m) * r * gv.z + bv.z;
    o.w = (v.w - m) * r * gv.w + bv.w;
    reinterpret_cast<float4*>(y + (size_t)row * D)[t] = o;
    ushort4 h; h.x = f2bf(o.x); h.y = f2bf(o.y); h.z = f2bf(o.z); h.w = f2bf(o.w);
    *reinterpret_cast<ushort4*>(yb + (size_t)row * D + t * 4) = h;
}

// ---------------- Kernel 2: q/k/v = id_ln @ W^T, bf16 MFMA 64x128 ----------
// Retiled 128x128 -> 64x128: grid (8, 32, 3) = 768 blocks = exactly 3/CU
// (was 384 = 1.5/CU -> 25% tail waste). Staging/compute pattern otherwise R0.
__global__ __launch_bounds__(256) void qkv_mfma_kernel(
    const unsigned short* __restrict__ idln, const unsigned short* __restrict__ Wb,
    unsigned short* __restrict__ q, unsigned short* __restrict__ k,
    unsigned short* __restrict__ vT)
{
    __shared__ unsigned short As[64 * 32];    // 4 KB
    __shared__ unsigned short Bs[128 * 32];   // 8 KB
    const int zi = blockIdx.z;
    const unsigned short* Bmat = Wb + (size_t)zi * D * D;
    const int m0 = blockIdx.y * 64, n0 = blockIdx.x * 128;
    const int t = threadIdx.x;
    const int w = t >> 6, lane = t & 63;
    const int wm = (w >> 1) * 32, wn = (w & 1) * 64;
    const int quad = lane >> 4, l16 = lane & 15;
    const int srow = t >> 2;          // 0..63
    const int scol = (t & 3) * 8;     // 0,8,16,24 (bf16 elems)

    f32x4 acc[2][4];
#pragma unroll
    for (int i = 0; i < 2; ++i)
#pragma unroll
        for (int j = 0; j < 4; ++j) acc[i][j] = (f32x4){0.f, 0.f, 0.f, 0.f};

    for (int k0 = 0; k0 < D; k0 += 32) {
        __syncthreads();
        {
            const unsigned short* ga = idln + (size_t)(m0 + srow) * D + k0 + scol;
            __builtin_amdgcn_global_load_lds((gptr_t)ga, (lptr_t)(As + t * 8), 16, 0, 0);
        }
#pragma unroll
        for (int c = 0; c < 2; ++c) {
            const unsigned short* gb = Bmat + (size_t)(n0 + srow + c * 64) * D + k0 + scol;
            __builtin_amdgcn_global_load_lds((gptr_t)gb, (lptr_t)(Bs + t * 8 + c * 2048), 16, 0, 0);
        }
        __syncthreads();
        bf16x8 af[2], bfr[4];
#pragma unroll
        for (int i = 0; i < 2; ++i)
            af[i] = *reinterpret_cast<const bf16x8*>(As + (wm + i * 16 + l16) * 32 + quad * 8);
#pragma unroll
        for (int j = 0; j < 4; ++j)
            bfr[j] = *reinterpret_cast<const bf16x8*>(Bs + (wn + j * 16 + l16) * 32 + quad * 8);
#pragma unroll
        for (int i = 0; i < 2; ++i)
#pragma unroll
            for (int j = 0; j < 4; ++j)
                acc[i][j] = __builtin_amdgcn_mfma_f32_16x16x32_bf16(af[i], bfr[j], acc[i][j], 0, 0, 0);
    }

    if (zi < 2) {
        unsigned short* C = (zi == 0) ? q : k;
#pragma unroll
        for (int i = 0; i < 2; ++i)
#pragma unroll
            for (int j = 0; j < 4; ++j) {
                const int gcol = n0 + wn + j * 16 + l16;
#pragma unroll
                for (int reg = 0; reg < 4; ++reg) {
                    const int grow = m0 + wm + i * 16 + quad * 4 + reg;
                    C[(size_t)grow * D + gcol] = f2bf(acc[i][j][reg]);
                }
            }
    } else {
        const int b = m0 >> 10;
#pragma unroll
        for (int i = 0; i < 2; ++i)
#pragma unroll
            for (int j = 0; j < 4; ++j) {
                const int gcol = n0 + wn + j * 16 + l16;          // flat D index = h*64+dh
                const int srow0 = (m0 - b * S) + wm + i * 16 + quad * 4;
                ushort4 h;
                h.x = f2bf(acc[i][j][0]); h.y = f2bf(acc[i][j][1]);
                h.z = f2bf(acc[i][j][2]); h.w = f2bf(acc[i][j][3]);
                *reinterpret_cast<ushort4*>(vT + ((size_t)b * D + gcol) * S + srow0) = h;
            }
    }
}

// ------- Kernel 3: single-pass attention, register-P + 2-phase K/V dbuf -------
// Grid: (1, S/64, H*B). Block 256 = 4 waves; wave w owns q-rows m0+w*16..+15.
// vs R4: K/V staging double-buffered (STAGE(t+1) issued before compute(t)),
// ONE __syncthreads per iteration (was 2) — prefetch latency hides under
// the kt-loop's MFMA+exp work. Fragment layouts byte-identical to R4.
__global__ __launch_bounds__(256, 2) void attn_fused_kernel(
    const unsigned short* __restrict__ q, const unsigned short* __restrict__ k,
    const unsigned short* __restrict__ vT, float* __restrict__ Aout,
    float* __restrict__ O)
{
    __shared__ unsigned short Qs[2 * 64 * 32];       // [c][qrow][32dh]      8 KB
    __shared__ unsigned short Ks[2][2 * 64 * 32];    // dbuf [c][key][32dh] 16 KB
    __shared__ unsigned short Vs[2][4 * 64 * 16];    // dbuf [kt][dh][16k]  16 KB

    const int z = blockIdx.z;            // z = h*B + b (head-major A layout)
    const int b = z & 1, h = z >> 1;
    const int m0 = blockIdx.y * 64;
    const int t = threadIdx.x;
    const int w = t >> 6, lane = t & 63;
    const int quad = lane >> 4, l16 = lane & 15;
    const int sr = t >> 2, sc8 = (t & 3) * 8;

    auto STAGE = [&](int n0, int bb) {
#pragma unroll
        for (int c = 0; c < 2; ++c) {
            const unsigned short* gk = k + (size_t)(b * S + n0 + sr) * D + h * DH + c * 32 + sc8;
            __builtin_amdgcn_global_load_lds((gptr_t)gk, (lptr_t)(Ks[bb] + c * 2048 + t * 8), 16, 0, 0);
        }
#pragma unroll
        for (int c2 = 0; c2 < 2; ++c2) {
            const int kt = c2 * 2 + (t >> 7);
            const int dh = (t >> 1) & 63;
            const int kh = t & 1;
            const unsigned short* gv = vT + ((size_t)b * D + h * DH + dh) * S + n0 + kt * 16 + kh * 8;
            __builtin_amdgcn_global_load_lds((gptr_t)gv, (lptr_t)(Vs[bb] + c2 * 2048 + t * 8), 16, 0, 0);
        }
    };

    // prologue: stage Q (once) + K/V tile 0; single barrier
#pragma unroll
    for (int c = 0; c < 2; ++c) {
        const unsigned short* gq = q + (size_t)(b * S + m0 + sr) * D + h * DH + c * 32 + sc8;
        __builtin_amdgcn_global_load_lds((gptr_t)gq, (lptr_t)(Qs + c * 2048 + t * 8), 16, 0, 0);
    }
    STAGE(0, 0);
    __syncthreads();
    // hoist Q B-frags (q = w*16 + l16, dh = c*32 + quad*8..+7)
    bf16x8 qf[2];
#pragma unroll
    for (int c = 0; c < 2; ++c)
        qf[c] = *reinterpret_cast<const bf16x8*>(Qs + c * 2048 + (w * 16 + l16) * 32 + quad * 8);

    f32x4 accO[4];
#pragma unroll
    for (int jj = 0; jj < 4; ++jj) accO[jj] = (f32x4){0.f, 0.f, 0.f, 0.f};
    float rsum = 0.f;
    uint2 pst[64];                        // [tt*4+kt] packed bf16 P fragment
    int cur = 0;

    // ---------------- single pass over key tiles, 2-phase dbuf ----------------
#pragma unroll
    for (int tt = 0; tt < 16; ++tt) {
        if (tt < 15) STAGE((tt + 1) * 64, cur ^ 1);
#pragma unroll
        for (int kt = 0; kt < 4; ++kt) {
            f32x4 a = (f32x4){0.f, 0.f, 0.f, 0.f};
#pragma unroll
            for (int c = 0; c < 2; ++c) {
                bf16x8 kf = *reinterpret_cast<const bf16x8*>(Ks[cur] + c * 2048 + (kt * 16 + l16) * 32 + quad * 8);
                a = __builtin_amdgcn_mfma_f32_16x16x32_bf16(kf, qf[c], a, 0, 0, 0);
            }
            const float e0 = __expf(a[0] * 0.125f);
            const float e1 = __expf(a[1] * 0.125f);
            const float e2 = __expf(a[2] * 0.125f);
            const float e3 = __expf(a[3] * 0.125f);
            rsum += (e0 + e1) + (e2 + e3);
            // pack P a-frag (unnormalized): A[m=q=l16][k=key=quad*4+j]
            bf16x4 p;
            p[0] = (short)f2bf(e0); p[1] = (short)f2bf(e1);
            p[2] = (short)f2bf(e2); p[3] = (short)f2bf(e3);
            pst[tt * 4 + kt] = *reinterpret_cast<uint2*>(&p);   // compile-time index
#pragma unroll
            for (int jj = 0; jj < 4; ++jj) {
                bf16x4 vv = *reinterpret_cast<const bf16x4*>(Vs[cur] + kt * 1024 + (jj * 16 + l16) * 16 + quad * 4);
                accO[jj] = __builtin_amdgcn_mfma_f32_16x16x16bf16_1k(p, vv, accO[jj], 0, 0, 0);
            }
        }
        __syncthreads();   // compute(cur) done by all; stage(cur^1) landed
        cur ^= 1;
    }

    // ---------------- epilogue: normalize ----------------
    rsum += __shfl_xor(rsum, 16, 64);
    rsum += __shfl_xor(rsum, 32, 64);
    const float sL = 1.0f / rsum;        // full sum for q-row l16, every lane
    float sO[4];
#pragma unroll
    for (int r = 0; r < 4; ++r) sO[r] = __shfl(sL, quad * 4 + r, 64);  // rows quad*4+r

    // write A: lane's q-row = l16, keys tt*64 + kt*16 + quad*4..+3 (16B stores)
    float* Az = Aout + (size_t)z * S * S + (size_t)(m0 + w * 16 + l16) * S;
#pragma unroll
    for (int tt = 0; tt < 16; ++tt)
#pragma unroll
        for (int kt = 0; kt < 4; ++kt) {
            const uint2 u = pst[tt * 4 + kt];
            *reinterpret_cast<float4*>(Az + tt * 64 + kt * 16 + quad * 4) =
                make_float4(bflo(u.x) * sL, bfhi(u.x) * sL, bflo(u.y) * sL, bfhi(u.y) * sL);
        }

    // write O: D row = q = quad*4+r (within wave's 16 rows), col dh = jj*16+l16
#pragma unroll
    for (int jj = 0; jj < 4; ++jj)
#pragma unroll
        for (int r = 0; r < 4; ++r) {
            const int grow = b * S + m0 + w * 16 + quad * 4 + r;
            O[(size_t)grow * D + h * DH + jj * 16 + l16] = accO[jj][r] * sO[r];
        }
}

// ---------------- Kernel 4: out = LN(id_ln+O,g1,b1) + LN(id+O,g2,b2) ----------
__global__ __launch_bounds__(256) void final_kernel(
    const float* __restrict__ id, const float* __restrict__ id_ln, const float* __restrict__ O,
    const float* __restrict__ g1, const float* __restrict__ b1,
    const float* __restrict__ g2, const float* __restrict__ b2,
    float* __restrict__ out)
{
    __shared__ float sm[16];
    __shared__ float stats[4];
    const int row = blockIdx.x;
    const int t = threadIdx.x;
    const size_t base = (size_t)row * D;
    const float4 xi = reinterpret_cast<const float4*>(id + base)[t];
    const float4 xl = reinterpret_cast<const float4*>(id_ln + base)[t];
    const float4 xo = reinterpret_cast<const float4*>(O + base)[t];
    float4 t1, t2;
    t1.x = xl.x + xo.x; t1.y = xl.y + xo.y; t1.z = xl.z + xo.z; t1.w = xl.w + xo.w;
    t2.x = xi.x + xo.x; t2.y = xi.y + xo.y; t2.z = xi.z + xo.z; t2.w = xi.w + xo.w;
    float s1  = t1.x + t1.y + t1.z + t1.w;
    float ss1 = t1.x*t1.x + t1.y*t1.y + t1.z*t1.z + t1.w*t1.w;
    float s2  = t2.x + t2.y + t2.z + t2.w;
    float ss2 = t2.x*t2.x + t2.y*t2.y + t2.z*t2.z + t2.w*t2.w;
    s1 = wave_sum(s1); ss1 = wave_sum(ss1);
    s2 = wave_sum(s2); ss2 = wave_sum(ss2);
    const int lane = t & 63, wid = t >> 6;
    if (lane == 0) { sm[wid] = s1; sm[4+wid] = ss1; sm[8+wid] = s2; sm[12+wid] = ss2; }
    __syncthreads();
    if (t == 0) {
        float S1 = sm[0]+sm[1]+sm[2]+sm[3];
        float Q1 = sm[4]+sm[5]+sm[6]+sm[7];
        float S2 = sm[8]+sm[9]+sm[10]+sm[11];
        float Q2 = sm[12]+sm[13]+sm[14]+sm[15];
        float m1 = S1 * (1.0f / D);
        float m2 = S2 * (1.0f / D);
        stats[0] = m1; stats[1] = rsqrtf(Q1 * (1.0f / D) - m1*m1 + EPS);
        stats[2] = m2; stats[3] = rsqrtf(Q2 * (1.0f / D) - m2*m2 + EPS);
    }
    __syncthreads();
    const float m1 = stats[0], r1 = stats[1], m2 = stats[2], r2 = stats[3];
    const float4 g1v = reinterpret_cast<const float4*>(g1)[t];
    const float4 b1v = reinterpret_cast<const float4*>(b1)[t];
    const float4 g2v = reinterpret_cast<const float4*>(g2)[t];
    const float4 b2v = reinterpret_cast<const float4*>(b2)[t];
    float4 o;
    o.x = (t1.x - m1)*r1*g1v.x + b1v.x + (t2.x - m2)*r2*g2v.x + b2v.x;
    o.y = (t1.y - m1)*r1*g1v.y + b1v.y + (t2.y - m2)*r2*g2v.y + b2v.y;
    o.z = (t1.z - m1)*r1*g1v.z + b1v.z + (t2.z - m2)*r2*g2v.z + b2v.z;
    o.w = (t1.w - m1)*r1*g1v.w + b1v.w + (t2.w - m2)*r2*g2v.w + b2v.w;
    reinterpret_cast<float4*>(out + base)[t] = o;
}

}  // namespace

extern "C" void kernel_launch(void* const* d_in, const int* in_sizes, int n_in,
                              void* d_out, int out_size, void* d_ws, size_t ws_size,
                              hipStream_t stream)
{
    const float* id = (const float*)d_in[0];
    const float* Wq = (const float*)d_in[1];
    const float* Wk = (const float*)d_in[2];
    const float* Wv = (const float*)d_in[3];
    const float* g0 = (const float*)d_in[4];
    const float* b0 = (const float*)d_in[5];
    const float* g1 = (const float*)d_in[6];
    const float* b1 = (const float*)d_in[7];
    const float* g2 = (const float*)d_in[8];
    const float* b2 = (const float*)d_in[9];

    float* out  = (float*)d_out;
    float* Aout = out + (size_t)B * S * D;   // A region [H*B, S, S], written once by attn

    char* ws = (char*)d_ws;
    float* id_ln  = (float*)(ws);                          //  8 MiB fp32
    float* O      = (float*)(ws + (8u << 20));             //  8 MiB fp32
    unsigned short* idln_bf = (unsigned short*)(ws + (16u << 20)); // 4 MiB
    unsigned short* Wb      = idln_bf + (size_t)M * D;     //  6 MiB (3 x DxD bf16)
    unsigned short* qb      = Wb + (size_t)3 * D * D;      //  4 MiB
    unsigned short* kb      = qb + (size_t)M * D;          //  4 MiB
    unsigned short* vT      = kb + (size_t)M * D;          //  4 MiB  [B][D][S]

    hipLaunchKernelGGL(pre_kernel, dim3(3072 + M), dim3(256), 0, stream,
                       Wq, Wk, Wv, Wb, id, g0, b0, id_ln, idln_bf);
    hipLaunchKernelGGL(qkv_mfma_kernel, dim3(D / 128, M / 64, 3), dim3(256), 0, stream,
                       idln_bf, Wb, qb, kb, vT);
    hipLaunchKernelGGL(attn_fused_kernel, dim3(1, S / 64, H * B), dim3(256), 0, stream,
                       qb, kb, vT, Aout, O);
    hipLaunchKernelGGL(final_kernel, dim3(M), dim3(256), 0, stream,
                       id, id_ln, O, g1, b1, g2, b2, out);
}

// Round 6
// 250.034 us; speedup vs baseline: 1.0709x; 1.0709x over previous
//
#include <hip/hip_runtime.h>

namespace {

constexpr int B = 2, S = 1024, D = 1024, H = 16, DH = 64;
constexpr int M = B * S;  // 2048 rows
constexpr float EPS = 1e-5f;

using bf16x8 = __attribute__((ext_vector_type(8))) short;  // MFMA A/B frag, K=32 (4 VGPRs)
using bf16x4 = __attribute__((ext_vector_type(4))) short;  // MFMA A/B frag, K=16 (2 VGPRs)
using f32x4  = __attribute__((ext_vector_type(4))) float;  // MFMA C/D frag

typedef const __attribute__((address_space(1))) void* gptr_t;
typedef __attribute__((address_space(3))) void* lptr_t;

__device__ __forceinline__ unsigned short f2bf(float f) {
    union { float f; unsigned u; } v{f};
    unsigned r = v.u + 0x7fffu + ((v.u >> 16) & 1u);  // RNE
    return (unsigned short)(r >> 16);
}

__device__ __forceinline__ float bflo(unsigned u) {
    union { unsigned u; float f; } v{u << 16}; return v.f;
}
__device__ __forceinline__ float bfhi(unsigned u) {
    union { unsigned u; float f; } v{u & 0xffff0000u}; return v.f;
}

__device__ __forceinline__ float wave_sum(float v) {
#pragma unroll
    for (int off = 32; off > 0; off >>= 1) v += __shfl_down(v, off, 64);
    return v;
}

// ------- Kernel 0+1 fused: W fp32->bf16 (blocks 0..3071) | LN0 (blocks 3072..5119) -------
__global__ __launch_bounds__(256) void pre_kernel(
    const float* __restrict__ Wq, const float* __restrict__ Wk,
    const float* __restrict__ Wv, unsigned short* __restrict__ Wb,
    const float* __restrict__ x, const float* __restrict__ g,
    const float* __restrict__ bt, float* __restrict__ y,
    unsigned short* __restrict__ yb)
{
    const int bx = blockIdx.x;
    const int t = threadIdx.x;
    if (bx < 3072) {
        const int z = bx >> 10;
        const float* src = (z == 0) ? Wq : (z == 1) ? Wk : Wv;
        const size_t i = ((size_t)(bx & 1023) * 256 + t) * 4;
        float4 f = *reinterpret_cast<const float4*>(src + i);
        ushort4 h;
        h.x = f2bf(f.x); h.y = f2bf(f.y); h.z = f2bf(f.z); h.w = f2bf(f.w);
        *reinterpret_cast<ushort4*>(Wb + (size_t)z * D * D + i) = h;
        return;
    }
    __shared__ float sm[8];
    __shared__ float stats[2];
    const int row = bx - 3072;
    const float4 v = reinterpret_cast<const float4*>(x + (size_t)row * D)[t];
    float s  = v.x + v.y + v.z + v.w;
    float ss = v.x*v.x + v.y*v.y + v.z*v.z + v.w*v.w;
    s = wave_sum(s); ss = wave_sum(ss);
    const int lane = t & 63, wid = t >> 6;
    if (lane == 0) { sm[wid] = s; sm[4 + wid] = ss; }
    __syncthreads();
    if (t == 0) {
        float S1 = sm[0] + sm[1] + sm[2] + sm[3];
        float S2 = sm[4] + sm[5] + sm[6] + sm[7];
        float m  = S1 * (1.0f / D);
        float var = S2 * (1.0f / D) - m * m;
        stats[0] = m; stats[1] = rsqrtf(var + EPS);
    }
    __syncthreads();
    const float m = stats[0], r = stats[1];
    const float4 gv = reinterpret_cast<const float4*>(g)[t];
    const float4 bv = reinterpret_cast<const float4*>(bt)[t];
    float4 o;
    o.x = (v.x - m) * r * gv.x + bv.x;
    o.y = (v.y - m) * r * gv.y + bv.y;
    o.z = (v.z - m) * r * gv.z + bv.z;
    o.w = (v.w - m) * r * gv.w + bv.w;
    reinterpret_cast<float4*>(y + (size_t)row * D)[t] = o;
    ushort4 h; h.x = f2bf(o.x); h.y = f2bf(o.y); h.z = f2bf(o.z); h.w = f2bf(o.w);
    *reinterpret_cast<ushort4*>(yb + (size_t)row * D + t * 4) = h;
}

// ---------------- Kernel 2: q/k/v = id_ln @ W^T, bf16 MFMA 64x128 ----------
// Retiled 128x128 -> 64x128: grid (8, 32, 3) = 768 blocks = exactly 3/CU
// (was 384 = 1.5/CU -> 25% tail waste). Staging/compute pattern otherwise R0.
__global__ __launch_bounds__(256) void qkv_mfma_kernel(
    const unsigned short* __restrict__ idln, const unsigned short* __restrict__ Wb,
    unsigned short* __restrict__ q, unsigned short* __restrict__ k,
    unsigned short* __restrict__ vT)
{
    __shared__ unsigned short As[64 * 32];    // 4 KB
    __shared__ unsigned short Bs[128 * 32];   // 8 KB
    const int zi = blockIdx.z;
    const unsigned short* Bmat = Wb + (size_t)zi * D * D;
    const int m0 = blockIdx.y * 64, n0 = blockIdx.x * 128;
    const int t = threadIdx.x;
    const int w = t >> 6, lane = t & 63;
    const int wm = (w >> 1) * 32, wn = (w & 1) * 64;
    const int quad = lane >> 4, l16 = lane & 15;
    const int srow = t >> 2;          // 0..63
    const int scol = (t & 3) * 8;     // 0,8,16,24 (bf16 elems)

    f32x4 acc[2][4];
#pragma unroll
    for (int i = 0; i < 2; ++i)
#pragma unroll
        for (int j = 0; j < 4; ++j) acc[i][j] = (f32x4){0.f, 0.f, 0.f, 0.f};

    for (int k0 = 0; k0 < D; k0 += 32) {
        __syncthreads();
        {
            const unsigned short* ga = idln + (size_t)(m0 + srow) * D + k0 + scol;
            __builtin_amdgcn_global_load_lds((gptr_t)ga, (lptr_t)(As + t * 8), 16, 0, 0);
        }
#pragma unroll
        for (int c = 0; c < 2; ++c) {
            const unsigned short* gb = Bmat + (size_t)(n0 + srow + c * 64) * D + k0 + scol;
            __builtin_amdgcn_global_load_lds((gptr_t)gb, (lptr_t)(Bs + t * 8 + c * 2048), 16, 0, 0);
        }
        __syncthreads();
        bf16x8 af[2], bfr[4];
#pragma unroll
        for (int i = 0; i < 2; ++i)
            af[i] = *reinterpret_cast<const bf16x8*>(As + (wm + i * 16 + l16) * 32 + quad * 8);
#pragma unroll
        for (int j = 0; j < 4; ++j)
            bfr[j] = *reinterpret_cast<const bf16x8*>(Bs + (wn + j * 16 + l16) * 32 + quad * 8);
#pragma unroll
        for (int i = 0; i < 2; ++i)
#pragma unroll
            for (int j = 0; j < 4; ++j)
                acc[i][j] = __builtin_amdgcn_mfma_f32_16x16x32_bf16(af[i], bfr[j], acc[i][j], 0, 0, 0);
    }

    if (zi < 2) {
        unsigned short* C = (zi == 0) ? q : k;
#pragma unroll
        for (int i = 0; i < 2; ++i)
#pragma unroll
            for (int j = 0; j < 4; ++j) {
                const int gcol = n0 + wn + j * 16 + l16;
#pragma unroll
                for (int reg = 0; reg < 4; ++reg) {
                    const int grow = m0 + wm + i * 16 + quad * 4 + reg;
                    C[(size_t)grow * D + gcol] = f2bf(acc[i][j][reg]);
                }
            }
    } else {
        const int b = m0 >> 10;
#pragma unroll
        for (int i = 0; i < 2; ++i)
#pragma unroll
            for (int j = 0; j < 4; ++j) {
                const int gcol = n0 + wn + j * 16 + l16;          // flat D index = h*64+dh
                const int srow0 = (m0 - b * S) + wm + i * 16 + quad * 4;
                ushort4 h;
                h.x = f2bf(acc[i][j][0]); h.y = f2bf(acc[i][j][1]);
                h.z = f2bf(acc[i][j][2]); h.w = f2bf(acc[i][j][3]);
                *reinterpret_cast<ushort4*>(vT + ((size_t)b * D + gcol) * S + srow0) = h;
            }
    }
}

// ------- Kernel 3: single-pass attention, register-P + 2-phase K/V dbuf -------
// Grid: (1, S/64, H*B). Block 256 = 4 waves; wave w owns q-rows m0+w*16..+15.
// vs R5: __launch_bounds__(256, 1). R5's (256,2) made the allocator cap at
// 128 VGPR and SPILL pst[64] (uint2 = 128 VGPR) to scratch — counter-proven:
// VGPR_Count=128, FETCH 77MB / WRITE 225MB vs expected 12/136 (excess == pst
// spill traffic, 67MB each way). With min-waves=1 the budget is 512; ~190
// VGPR lands at 2 waves/SIMD at runtime (same occupancy, zero scratch).
__global__ __launch_bounds__(256, 1) void attn_fused_kernel(
    const unsigned short* __restrict__ q, const unsigned short* __restrict__ k,
    const unsigned short* __restrict__ vT, float* __restrict__ Aout,
    float* __restrict__ O)
{
    __shared__ unsigned short Qs[2 * 64 * 32];       // [c][qrow][32dh]      8 KB
    __shared__ unsigned short Ks[2][2 * 64 * 32];    // dbuf [c][key][32dh] 16 KB
    __shared__ unsigned short Vs[2][4 * 64 * 16];    // dbuf [kt][dh][16k]  16 KB

    const int z = blockIdx.z;            // z = h*B + b (head-major A layout)
    const int b = z & 1, h = z >> 1;
    const int m0 = blockIdx.y * 64;
    const int t = threadIdx.x;
    const int w = t >> 6, lane = t & 63;
    const int quad = lane >> 4, l16 = lane & 15;
    const int sr = t >> 2, sc8 = (t & 3) * 8;

    auto STAGE = [&](int n0, int bb) {
#pragma unroll
        for (int c = 0; c < 2; ++c) {
            const unsigned short* gk = k + (size_t)(b * S + n0 + sr) * D + h * DH + c * 32 + sc8;
            __builtin_amdgcn_global_load_lds((gptr_t)gk, (lptr_t)(Ks[bb] + c * 2048 + t * 8), 16, 0, 0);
        }
#pragma unroll
        for (int c2 = 0; c2 < 2; ++c2) {
            const int kt = c2 * 2 + (t >> 7);
            const int dh = (t >> 1) & 63;
            const int kh = t & 1;
            const unsigned short* gv = vT + ((size_t)b * D + h * DH + dh) * S + n0 + kt * 16 + kh * 8;
            __builtin_amdgcn_global_load_lds((gptr_t)gv, (lptr_t)(Vs[bb] + c2 * 2048 + t * 8), 16, 0, 0);
        }
    };

    // prologue: stage Q (once) + K/V tile 0; single barrier
#pragma unroll
    for (int c = 0; c < 2; ++c) {
        const unsigned short* gq = q + (size_t)(b * S + m0 + sr) * D + h * DH + c * 32 + sc8;
        __builtin_amdgcn_global_load_lds((gptr_t)gq, (lptr_t)(Qs + c * 2048 + t * 8), 16, 0, 0);
    }
    STAGE(0, 0);
    __syncthreads();
    // hoist Q B-frags (q = w*16 + l16, dh = c*32 + quad*8..+7)
    bf16x8 qf[2];
#pragma unroll
    for (int c = 0; c < 2; ++c)
        qf[c] = *reinterpret_cast<const bf16x8*>(Qs + c * 2048 + (w * 16 + l16) * 32 + quad * 8);

    f32x4 accO[4];
#pragma unroll
    for (int jj = 0; jj < 4; ++jj) accO[jj] = (f32x4){0.f, 0.f, 0.f, 0.f};
    float rsum = 0.f;
    uint2 pst[64];                        // [tt*4+kt] packed bf16 P fragment
    int cur = 0;

    // ---------------- single pass over key tiles, 2-phase dbuf ----------------
#pragma unroll
    for (int tt = 0; tt < 16; ++tt) {
        if (tt < 15) STAGE((tt + 1) * 64, cur ^ 1);
#pragma unroll
        for (int kt = 0; kt < 4; ++kt) {
            f32x4 a = (f32x4){0.f, 0.f, 0.f, 0.f};
#pragma unroll
            for (int c = 0; c < 2; ++c) {
                bf16x8 kf = *reinterpret_cast<const bf16x8*>(Ks[cur] + c * 2048 + (kt * 16 + l16) * 32 + quad * 8);
                a = __builtin_amdgcn_mfma_f32_16x16x32_bf16(kf, qf[c], a, 0, 0, 0);
            }
            const float e0 = __expf(a[0] * 0.125f);
            const float e1 = __expf(a[1] * 0.125f);
            const float e2 = __expf(a[2] * 0.125f);
            const float e3 = __expf(a[3] * 0.125f);
            rsum += (e0 + e1) + (e2 + e3);
            // pack P a-frag (unnormalized): A[m=q=l16][k=key=quad*4+j]
            bf16x4 p;
            p[0] = (short)f2bf(e0); p[1] = (short)f2bf(e1);
            p[2] = (short)f2bf(e2); p[3] = (short)f2bf(e3);
            pst[tt * 4 + kt] = *reinterpret_cast<uint2*>(&p);   // compile-time index
#pragma unroll
            for (int jj = 0; jj < 4; ++jj) {
                bf16x4 vv = *reinterpret_cast<const bf16x4*>(Vs[cur] + kt * 1024 + (jj * 16 + l16) * 16 + quad * 4);
                accO[jj] = __builtin_amdgcn_mfma_f32_16x16x16bf16_1k(p, vv, accO[jj], 0, 0, 0);
            }
        }
        __syncthreads();   // compute(cur) done by all; stage(cur^1) landed
        cur ^= 1;
    }

    // ---------------- epilogue: normalize ----------------
    rsum += __shfl_xor(rsum, 16, 64);
    rsum += __shfl_xor(rsum, 32, 64);
    const float sL = 1.0f / rsum;        // full sum for q-row l16, every lane
    float sO[4];
#pragma unroll
    for (int r = 0; r < 4; ++r) sO[r] = __shfl(sL, quad * 4 + r, 64);  // rows quad*4+r

    // write A: lane's q-row = l16, keys tt*64 + kt*16 + quad*4..+3 (16B stores)
    float* Az = Aout + (size_t)z * S * S + (size_t)(m0 + w * 16 + l16) * S;
#pragma unroll
    for (int tt = 0; tt < 16; ++tt)
#pragma unroll
        for (int kt = 0; kt < 4; ++kt) {
            const uint2 u = pst[tt * 4 + kt];
            *reinterpret_cast<float4*>(Az + tt * 64 + kt * 16 + quad * 4) =
                make_float4(bflo(u.x) * sL, bfhi(u.x) * sL, bflo(u.y) * sL, bfhi(u.y) * sL);
        }

    // write O: D row = q = quad*4+r (within wave's 16 rows), col dh = jj*16+l16
#pragma unroll
    for (int jj = 0; jj < 4; ++jj)
#pragma unroll
        for (int r = 0; r < 4; ++r) {
            const int grow = b * S + m0 + w * 16 + quad * 4 + r;
            O[(size_t)grow * D + h * DH + jj * 16 + l16] = accO[jj][r] * sO[r];
        }
}

// ---------------- Kernel 4: out = LN(id_ln+O,g1,b1) + LN(id+O,g2,b2) ----------
__global__ __launch_bounds__(256) void final_kernel(
    const float* __restrict__ id, const float* __restrict__ id_ln, const float* __restrict__ O,
    const float* __restrict__ g1, const float* __restrict__ b1,
    const float* __restrict__ g2, const float* __restrict__ b2,
    float* __restrict__ out)
{
    __shared__ float sm[16];
    __shared__ float stats[4];
    const int row = blockIdx.x;
    const int t = threadIdx.x;
    const size_t base = (size_t)row * D;
    const float4 xi = reinterpret_cast<const float4*>(id + base)[t];
    const float4 xl = reinterpret_cast<const float4*>(id_ln + base)[t];
    const float4 xo = reinterpret_cast<const float4*>(O + base)[t];
    float4 t1, t2;
    t1.x = xl.x + xo.x; t1.y = xl.y + xo.y; t1.z = xl.z + xo.z; t1.w = xl.w + xo.w;
    t2.x = xi.x + xo.x; t2.y = xi.y + xo.y; t2.z = xi.z + xo.z; t2.w = xi.w + xo.w;
    float s1  = t1.x + t1.y + t1.z + t1.w;
    float ss1 = t1.x*t1.x + t1.y*t1.y + t1.z*t1.z + t1.w*t1.w;
    float s2  = t2.x + t2.y + t2.z + t2.w;
    float ss2 = t2.x*t2.x + t2.y*t2.y + t2.z*t2.z + t2.w*t2.w;
    s1 = wave_sum(s1); ss1 = wave_sum(ss1);
    s2 = wave_sum(s2); ss2 = wave_sum(ss2);
    const int lane = t & 63, wid = t >> 6;
    if (lane == 0) { sm[wid] = s1; sm[4+wid] = ss1; sm[8+wid] = s2; sm[12+wid] = ss2; }
    __syncthreads();
    if (t == 0) {
        float S1 = sm[0]+sm[1]+sm[2]+sm[3];
        float Q1 = sm[4]+sm[5]+sm[6]+sm[7];
        float S2 = sm[8]+sm[9]+sm[10]+sm[11];
        float Q2 = sm[12]+sm[13]+sm[14]+sm[15];
        float m1 = S1 * (1.0f / D);
        float m2 = S2 * (1.0f / D);
        stats[0] = m1; stats[1] = rsqrtf(Q1 * (1.0f / D) - m1*m1 + EPS);
        stats[2] = m2; stats[3] = rsqrtf(Q2 * (1.0f / D) - m2*m2 + EPS);
    }
    __syncthreads();
    const float m1 = stats[0], r1 = stats[1], m2 = stats[2], r2 = stats[3];
    const float4 g1v = reinterpret_cast<const float4*>(g1)[t];
    const float4 b1v = reinterpret_cast<const float4*>(b1)[t];
    const float4 g2v = reinterpret_cast<const float4*>(g2)[t];
    const float4 b2v = reinterpret_cast<const float4*>(b2)[t];
    float4 o;
    o.x = (t1.x - m1)*r1*g1v.x + b1v.x + (t2.x - m2)*r2*g2v.x + b2v.x;
    o.y = (t1.y - m1)*r1*g1v.y + b1v.y + (t2.y - m2)*r2*g2v.y + b2v.y;
    o.z = (t1.z - m1)*r1*g1v.z + b1v.z + (t2.z - m2)*r2*g2v.z + b2v.z;
    o.w = (t1.w - m1)*r1*g1v.w + b1v.w + (t2.w - m2)*r2*g2v.w + b2v.w;
    reinterpret_cast<float4*>(out + base)[t] = o;
}

}  // namespace

extern "C" void kernel_launch(void* const* d_in, const int* in_sizes, int n_in,
                              void* d_out, int out_size, void* d_ws, size_t ws_size,
                              hipStream_t stream)
{
    const float* id = (const float*)d_in[0];
    const float* Wq = (const float*)d_in[1];
    const float* Wk = (const float*)d_in[2];
    const float* Wv = (const float*)d_in[3];
    const float* g0 = (const float*)d_in[4];
    const float* b0 = (const float*)d_in[5];
    const float* g1 = (const float*)d_in[6];
    const float* b1 = (const float*)d_in[7];
    const float* g2 = (const float*)d_in[8];
    const float* b2 = (const float*)d_in[9];

    float* out  = (float*)d_out;
    float* Aout = out + (size_t)B * S * D;   // A region [H*B, S, S], written once by attn

    char* ws = (char*)d_ws;
    float* id_ln  = (float*)(ws);                          //  8 MiB fp32
    float* O      = (float*)(ws + (8u << 20));             //  8 MiB fp32
    unsigned short* idln_bf = (unsigned short*)(ws + (16u << 20)); // 4 MiB
    unsigned short* Wb      = idln_bf + (size_t)M * D;     //  6 MiB (3 x DxD bf16)
    unsigned short* qb      = Wb + (size_t)3 * D * D;      //  4 MiB
    unsigned short* kb      = qb + (size_t)M * D;          //  4 MiB
    unsigned short* vT      = kb + (size_t)M * D;          //  4 MiB  [B][D][S]

    hipLaunchKernelGGL(pre_kernel, dim3(3072 + M), dim3(256), 0, stream,
                       Wq, Wk, Wv, Wb, id, g0, b0, id_ln, idln_bf);
    hipLaunchKernelGGL(qkv_mfma_kernel, dim3(D / 128, M / 64, 3), dim3(256), 0, stream,
                       idln_bf, Wb, qb, kb, vT);
    hipLaunchKernelGGL(attn_fused_kernel, dim3(1, S / 64, H * B), dim3(256), 0, stream,
                       qb, kb, vT, Aout, O);
    hipLaunchKernelGGL(final_kernel, dim3(M), dim3(256), 0, stream,
                       id, id_ln, O, g1, b1, g2, b2, out);
}

// Round 7
// 241.519 us; speedup vs baseline: 1.1087x; 1.0353x over previous
//
#include <hip/hip_runtime.h>

namespace {

constexpr int B = 2, S = 1024, D = 1024, H = 16, DH = 64;
constexpr int M = B * S;  // 2048 rows
constexpr float EPS = 1e-5f;

using bf16x8 = __attribute__((ext_vector_type(8))) short;  // MFMA A/B frag, K=32 (4 VGPRs)
using bf16x4 = __attribute__((ext_vector_type(4))) short;  // MFMA A/B frag, K=16 (2 VGPRs)
using f32x4  = __attribute__((ext_vector_type(4))) float;  // MFMA C/D frag

typedef const __attribute__((address_space(1))) void* gptr_t;
typedef __attribute__((address_space(3))) void* lptr_t;

__device__ __forceinline__ unsigned short f2bf(float f) {
    union { float f; unsigned u; } v{f};
    unsigned r = v.u + 0x7fffu + ((v.u >> 16) & 1u);  // RNE
    return (unsigned short)(r >> 16);
}

__device__ __forceinline__ float bflo(unsigned u) {
    union { unsigned u; float f; } v{u << 16}; return v.f;
}
__device__ __forceinline__ float bfhi(unsigned u) {
    union { unsigned u; float f; } v{u & 0xffff0000u}; return v.f;
}

__device__ __forceinline__ float wave_sum(float v) {
#pragma unroll
    for (int off = 32; off > 0; off >>= 1) v += __shfl_down(v, off, 64);
    return v;
}

// ---------------- Kernel 0: W fp32 -> bf16 ----------------
__global__ __launch_bounds__(256) void cvt_w_kernel(
    const float* __restrict__ Wq, const float* __restrict__ Wk,
    const float* __restrict__ Wv, unsigned short* __restrict__ Wb)
{
    const float* src = (blockIdx.z == 0) ? Wq : (blockIdx.z == 1) ? Wk : Wv;
    const size_t i = ((size_t)blockIdx.x * 256 + threadIdx.x) * 4;
    float4 f = *reinterpret_cast<const float4*>(src + i);
    ushort4 h;
    h.x = f2bf(f.x); h.y = f2bf(f.y); h.z = f2bf(f.z); h.w = f2bf(f.w);
    *reinterpret_cast<ushort4*>(Wb + (size_t)blockIdx.z * D * D + i) = h;
}

// ---------------- Kernel 1: LN(id) -> id_ln (fp32 + bf16) ----------------
__global__ __launch_bounds__(256) void ln0_kernel(
    const float* __restrict__ x, const float* __restrict__ g,
    const float* __restrict__ bt, float* __restrict__ y,
    unsigned short* __restrict__ yb)
{
    __shared__ float sm[8];
    __shared__ float stats[2];
    const int row = blockIdx.x;
    const int t = threadIdx.x;
    const float4 v = reinterpret_cast<const float4*>(x + (size_t)row * D)[t];
    float s  = v.x + v.y + v.z + v.w;
    float ss = v.x*v.x + v.y*v.y + v.z*v.z + v.w*v.w;
    s = wave_sum(s); ss = wave_sum(ss);
    const int lane = t & 63, wid = t >> 6;
    if (lane == 0) { sm[wid] = s; sm[4 + wid] = ss; }
    __syncthreads();
    if (t == 0) {
        float S1 = sm[0] + sm[1] + sm[2] + sm[3];
        float S2 = sm[4] + sm[5] + sm[6] + sm[7];
        float m  = S1 * (1.0f / D);
        float var = S2 * (1.0f / D) - m * m;
        stats[0] = m; stats[1] = rsqrtf(var + EPS);
    }
    __syncthreads();
    const float m = stats[0], r = stats[1];
    const float4 gv = reinterpret_cast<const float4*>(g)[t];
    const float4 bv = reinterpret_cast<const float4*>(bt)[t];
    float4 o;
    o.x = (v.x - m) * r * gv.x + bv.x;
    o.y = (v.y - m) * r * gv.y + bv.y;
    o.z = (v.z - m) * r * gv.z + bv.z;
    o.w = (v.w - m) * r * gv.w + bv.w;
    reinterpret_cast<float4*>(y + (size_t)row * D)[t] = o;
    ushort4 h; h.x = f2bf(o.x); h.y = f2bf(o.y); h.z = f2bf(o.z); h.w = f2bf(o.w);
    *reinterpret_cast<ushort4*>(yb + (size_t)row * D + t * 4) = h;
}

// ---------------- Kernel 2: q/k/v = id_ln @ W^T, bf16 MFMA 128x128 ----------
// Byte-exact R0 baseline. (R6's 64x128 retile regressed: doubles B-panel
// traffic; 384 blocks already run 2-deep/CU so there was no tail waste.)
__global__ __launch_bounds__(256) void qkv_mfma_kernel(
    const unsigned short* __restrict__ idln, const unsigned short* __restrict__ Wb,
    unsigned short* __restrict__ q, unsigned short* __restrict__ k,
    unsigned short* __restrict__ vT)
{
    __shared__ unsigned short As[128 * 32];
    __shared__ unsigned short Bs[128 * 32];
    const int zi = blockIdx.z;
    const unsigned short* Bmat = Wb + (size_t)zi * D * D;
    const int m0 = blockIdx.y * 128, n0 = blockIdx.x * 128;
    const int t = threadIdx.x;
    const int w = t >> 6, lane = t & 63;
    const int wm = (w >> 1) * 64, wn = (w & 1) * 64;
    const int quad = lane >> 4, l16 = lane & 15;
    const int srow = t >> 2;          // 0..63
    const int scol = (t & 3) * 8;     // 0,8,16,24 (bf16 elems)

    f32x4 acc[4][4];
#pragma unroll
    for (int i = 0; i < 4; ++i)
#pragma unroll
        for (int j = 0; j < 4; ++j) acc[i][j] = (f32x4){0.f, 0.f, 0.f, 0.f};

    for (int k0 = 0; k0 < D; k0 += 32) {
        __syncthreads();
#pragma unroll
        for (int c = 0; c < 2; ++c) {
            const unsigned short* ga = idln + (size_t)(m0 + srow + c * 64) * D + k0 + scol;
            __builtin_amdgcn_global_load_lds((gptr_t)ga, (lptr_t)(As + t * 8 + c * 2048), 16, 0, 0);
            const unsigned short* gb = Bmat + (size_t)(n0 + srow + c * 64) * D + k0 + scol;
            __builtin_amdgcn_global_load_lds((gptr_t)gb, (lptr_t)(Bs + t * 8 + c * 2048), 16, 0, 0);
        }
        __syncthreads();
        bf16x8 af[4], bfr[4];
#pragma unroll
        for (int i = 0; i < 4; ++i)
            af[i] = *reinterpret_cast<const bf16x8*>(As + (wm + i * 16 + l16) * 32 + quad * 8);
#pragma unroll
        for (int j = 0; j < 4; ++j)
            bfr[j] = *reinterpret_cast<const bf16x8*>(Bs + (wn + j * 16 + l16) * 32 + quad * 8);
#pragma unroll
        for (int i = 0; i < 4; ++i)
#pragma unroll
            for (int j = 0; j < 4; ++j)
                acc[i][j] = __builtin_amdgcn_mfma_f32_16x16x32_bf16(af[i], bfr[j], acc[i][j], 0, 0, 0);
    }

    if (zi < 2) {
        unsigned short* C = (zi == 0) ? q : k;
#pragma unroll
        for (int i = 0; i < 4; ++i)
#pragma unroll
            for (int j = 0; j < 4; ++j) {
                const int gcol = n0 + wn + j * 16 + l16;
#pragma unroll
                for (int reg = 0; reg < 4; ++reg) {
                    const int grow = m0 + wm + i * 16 + quad * 4 + reg;
                    C[(size_t)grow * D + gcol] = f2bf(acc[i][j][reg]);
                }
            }
    } else {
        const int b = m0 >> 10;
#pragma unroll
        for (int i = 0; i < 4; ++i)
#pragma unroll
            for (int j = 0; j < 4; ++j) {
                const int gcol = n0 + wn + j * 16 + l16;          // flat D index = h*64+dh
                const int srow0 = (m0 - b * S) + wm + i * 16 + quad * 4;
                ushort4 h;
                h.x = f2bf(acc[i][j][0]); h.y = f2bf(acc[i][j][1]);
                h.z = f2bf(acc[i][j][2]); h.w = f2bf(acc[i][j][3]);
                *reinterpret_cast<ushort4*>(vT + ((size_t)b * D + gcol) * S + srow0) = h;
            }
    }
}

// ------- Kernel 3: single-pass attention, register-resident P (R4 base) -------
// Grid: (1, S/64, H*B). Block 256 = 4 waves; wave w owns q-rows m0+w*16..+15.
// ONLY change vs R4: __launch_bounds__ (256,2) -> (256,1). R5's counters
// proved (256,2) caps the allocator at 128 VGPR and spills pst[64] (needs
// 128 VGPR alone) to scratch: VGPR_Count=128, FETCH 77MB/WRITE 225MB vs
// expected 12/136 — excess == pst round-trip (67MB each way). R6 proved
// (256,1) removes it. Occupancy unchanged: grid = 2 blocks/CU = 2 waves/SIMD
// (grid-limited), and ~200 VGPR still fits 2 waves/SIMD.
__global__ __launch_bounds__(256, 1) void attn_fused_kernel(
    const unsigned short* __restrict__ q, const unsigned short* __restrict__ k,
    const unsigned short* __restrict__ vT, float* __restrict__ Aout,
    float* __restrict__ O)
{
    __shared__ unsigned short Qs[2 * 64 * 32];   // [c][qrow][32dh]
    __shared__ unsigned short Ks[2 * 64 * 32];   // [c][key][32dh]
    __shared__ unsigned short Vs[4 * 64 * 16];   // [kt][dh][16keys]

    const int z = blockIdx.z;            // z = h*B + b (head-major A layout)
    const int b = z & 1, h = z >> 1;
    const int m0 = blockIdx.y * 64;
    const int t = threadIdx.x;
    const int w = t >> 6, lane = t & 63;
    const int quad = lane >> 4, l16 = lane & 15;
    const int sr = t >> 2, sc8 = (t & 3) * 8;

    // stage Q tile (64 x 64) once: two c-slabs of [64][32]
#pragma unroll
    for (int c = 0; c < 2; ++c) {
        const unsigned short* gq = q + (size_t)(b * S + m0 + sr) * D + h * DH + c * 32 + sc8;
        __builtin_amdgcn_global_load_lds((gptr_t)gq, (lptr_t)(Qs + c * 2048 + t * 8), 16, 0, 0);
    }
    __syncthreads();
    // hoist Q B-frags (q = w*16 + l16, dh = c*32 + quad*8..+7)
    bf16x8 qf[2];
#pragma unroll
    for (int c = 0; c < 2; ++c)
        qf[c] = *reinterpret_cast<const bf16x8*>(Qs + c * 2048 + (w * 16 + l16) * 32 + quad * 8);

    f32x4 accO[4];
#pragma unroll
    for (int jj = 0; jj < 4; ++jj) accO[jj] = (f32x4){0.f, 0.f, 0.f, 0.f};
    float rsum = 0.f;
    uint2 pst[64];                        // [tt*4+kt] packed bf16 P fragment

    // ---------------- single pass over key tiles ----------------
#pragma unroll
    for (int tt = 0; tt < 16; ++tt) {
        const int n0 = tt * 64;
        __syncthreads();
#pragma unroll
        for (int c = 0; c < 2; ++c) {
            const unsigned short* gk = k + (size_t)(b * S + n0 + sr) * D + h * DH + c * 32 + sc8;
            __builtin_amdgcn_global_load_lds((gptr_t)gk, (lptr_t)(Ks + c * 2048 + t * 8), 16, 0, 0);
        }
        // stage V as 4 slabs [kt][dh][16keys]; 2 calls of 2 slabs each
#pragma unroll
        for (int c2 = 0; c2 < 2; ++c2) {
            const int kt = c2 * 2 + (t >> 7);
            const int dh = (t >> 1) & 63;
            const int kh = t & 1;
            const unsigned short* gv = vT + ((size_t)b * D + h * DH + dh) * S + n0 + kt * 16 + kh * 8;
            __builtin_amdgcn_global_load_lds((gptr_t)gv, (lptr_t)(Vs + c2 * 2048 + t * 8), 16, 0, 0);
        }
        __syncthreads();
#pragma unroll
        for (int kt = 0; kt < 4; ++kt) {
            f32x4 a = (f32x4){0.f, 0.f, 0.f, 0.f};
#pragma unroll
            for (int c = 0; c < 2; ++c) {
                bf16x8 kf = *reinterpret_cast<const bf16x8*>(Ks + c * 2048 + (kt * 16 + l16) * 32 + quad * 8);
                a = __builtin_amdgcn_mfma_f32_16x16x32_bf16(kf, qf[c], a, 0, 0, 0);
            }
            const float e0 = __expf(a[0] * 0.125f);
            const float e1 = __expf(a[1] * 0.125f);
            const float e2 = __expf(a[2] * 0.125f);
            const float e3 = __expf(a[3] * 0.125f);
            rsum += (e0 + e1) + (e2 + e3);
            // pack P a-frag (unnormalized): A[m=q=l16][k=key=quad*4+j]
            bf16x4 p;
            p[0] = (short)f2bf(e0); p[1] = (short)f2bf(e1);
            p[2] = (short)f2bf(e2); p[3] = (short)f2bf(e3);
            pst[tt * 4 + kt] = *reinterpret_cast<uint2*>(&p);   // compile-time index
#pragma unroll
            for (int jj = 0; jj < 4; ++jj) {
                bf16x4 vv = *reinterpret_cast<const bf16x4*>(Vs + kt * 1024 + (jj * 16 + l16) * 16 + quad * 4);
                accO[jj] = __builtin_amdgcn_mfma_f32_16x16x16bf16_1k(p, vv, accO[jj], 0, 0, 0);
            }
        }
    }

    // ---------------- epilogue: normalize ----------------
    rsum += __shfl_xor(rsum, 16, 64);
    rsum += __shfl_xor(rsum, 32, 64);
    const float sL = 1.0f / rsum;        // full sum for q-row l16, every lane
    float sO[4];
#pragma unroll
    for (int r = 0; r < 4; ++r) sO[r] = __shfl(sL, quad * 4 + r, 64);  // rows quad*4+r

    // write A: lane's q-row = l16, keys tt*64 + kt*16 + quad*4..+3 (16B stores)
    float* Az = Aout + (size_t)z * S * S + (size_t)(m0 + w * 16 + l16) * S;
#pragma unroll
    for (int tt = 0; tt < 16; ++tt)
#pragma unroll
        for (int kt = 0; kt < 4; ++kt) {
            const uint2 u = pst[tt * 4 + kt];
            *reinterpret_cast<float4*>(Az + tt * 64 + kt * 16 + quad * 4) =
                make_float4(bflo(u.x) * sL, bfhi(u.x) * sL, bflo(u.y) * sL, bfhi(u.y) * sL);
        }

    // write O: D row = q = quad*4+r (within wave's 16 rows), col dh = jj*16+l16
#pragma unroll
    for (int jj = 0; jj < 4; ++jj)
#pragma unroll
        for (int r = 0; r < 4; ++r) {
            const int grow = b * S + m0 + w * 16 + quad * 4 + r;
            O[(size_t)grow * D + h * DH + jj * 16 + l16] = accO[jj][r] * sO[r];
        }
}

// ---------------- Kernel 4: out = LN(id_ln+O,g1,b1) + LN(id+O,g2,b2) ----------
__global__ __launch_bounds__(256) void final_kernel(
    const float* __restrict__ id, const float* __restrict__ id_ln, const float* __restrict__ O,
    const float* __restrict__ g1, const float* __restrict__ b1,
    const float* __restrict__ g2, const float* __restrict__ b2,
    float* __restrict__ out)
{
    __shared__ float sm[16];
    __shared__ float stats[4];
    const int row = blockIdx.x;
    const int t = threadIdx.x;
    const size_t base = (size_t)row * D;
    const float4 xi = reinterpret_cast<const float4*>(id + base)[t];
    const float4 xl = reinterpret_cast<const float4*>(id_ln + base)[t];
    const float4 xo = reinterpret_cast<const float4*>(O + base)[t];
    float4 t1, t2;
    t1.x = xl.x + xo.x; t1.y = xl.y + xo.y; t1.z = xl.z + xo.z; t1.w = xl.w + xo.w;
    t2.x = xi.x + xo.x; t2.y = xi.y + xo.y; t2.z = xi.z + xo.z; t2.w = xi.w + xo.w;
    float s1  = t1.x + t1.y + t1.z + t1.w;
    float ss1 = t1.x*t1.x + t1.y*t1.y + t1.z*t1.z + t1.w*t1.w;
    float s2  = t2.x + t2.y + t2.z + t2.w;
    float ss2 = t2.x*t2.x + t2.y*t2.y + t2.z*t2.z + t2.w*t2.w;
    s1 = wave_sum(s1); ss1 = wave_sum(ss1);
    s2 = wave_sum(s2); ss2 = wave_sum(ss2);
    const int lane = t & 63, wid = t >> 6;
    if (lane == 0) { sm[wid] = s1; sm[4+wid] = ss1; sm[8+wid] = s2; sm[12+wid] = ss2; }
    __syncthreads();
    if (t == 0) {
        float S1 = sm[0]+sm[1]+sm[2]+sm[3];
        float Q1 = sm[4]+sm[5]+sm[6]+sm[7];
        float S2 = sm[8]+sm[9]+sm[10]+sm[11];
        float Q2 = sm[12]+sm[13]+sm[14]+sm[15];
        float m1 = S1 * (1.0f / D);
        float m2 = S2 * (1.0f / D);
        stats[0] = m1; stats[1] = rsqrtf(Q1 * (1.0f / D) - m1*m1 + EPS);
        stats[2] = m2; stats[3] = rsqrtf(Q2 * (1.0f / D) - m2*m2 + EPS);
    }
    __syncthreads();
    const float m1 = stats[0], r1 = stats[1], m2 = stats[2], r2 = stats[3];
    const float4 g1v = reinterpret_cast<const float4*>(g1)[t];
    const float4 b1v = reinterpret_cast<const float4*>(b1)[t];
    const float4 g2v = reinterpret_cast<const float4*>(g2)[t];
    const float4 b2v = reinterpret_cast<const float4*>(b2)[t];
    float4 o;
    o.x = (t1.x - m1)*r1*g1v.x + b1v.x + (t2.x - m2)*r2*g2v.x + b2v.x;
    o.y = (t1.y - m1)*r1*g1v.y + b1v.y + (t2.y - m2)*r2*g2v.y + b2v.y;
    o.z = (t1.z - m1)*r1*g1v.z + b1v.z + (t2.z - m2)*r2*g2v.z + b2v.z;
    o.w = (t1.w - m1)*r1*g1v.w + b1v.w + (t2.w - m2)*r2*g2v.w + b2v.w;
    reinterpret_cast<float4*>(out + base)[t] = o;
}

}  // namespace

extern "C" void kernel_launch(void* const* d_in, const int* in_sizes, int n_in,
                              void* d_out, int out_size, void* d_ws, size_t ws_size,
                              hipStream_t stream)
{
    const float* id = (const float*)d_in[0];
    const float* Wq = (const float*)d_in[1];
    const float* Wk = (const float*)d_in[2];
    const float* Wv = (const float*)d_in[3];
    const float* g0 = (const float*)d_in[4];
    const float* b0 = (const float*)d_in[5];
    const float* g1 = (const float*)d_in[6];
    const float* b1 = (const float*)d_in[7];
    const float* g2 = (const float*)d_in[8];
    const float* b2 = (const float*)d_in[9];

    float* out  = (float*)d_out;
    float* Aout = out + (size_t)B * S * D;   // A region [H*B, S, S], written once by attn

    char* ws = (char*)d_ws;
    float* id_ln  = (float*)(ws);                          //  8 MiB fp32
    float* O      = (float*)(ws + (8u << 20));             //  8 MiB fp32
    unsigned short* idln_bf = (unsigned short*)(ws + (16u << 20)); // 4 MiB
    unsigned short* Wb      = idln_bf + (size_t)M * D;     //  6 MiB (3 x DxD bf16)
    unsigned short* qb      = Wb + (size_t)3 * D * D;      //  4 MiB
    unsigned short* kb      = qb + (size_t)M * D;          //  4 MiB
    unsigned short* vT      = kb + (size_t)M * D;          //  4 MiB  [B][D][S]

    hipLaunchKernelGGL(cvt_w_kernel, dim3(D * D / 1024, 1, 3), dim3(256), 0, stream,
                       Wq, Wk, Wv, Wb);
    hipLaunchKernelGGL(ln0_kernel, dim3(M), dim3(256), 0, stream, id, g0, b0, id_ln, idln_bf);
    hipLaunchKernelGGL(qkv_mfma_kernel, dim3(D / 128, M / 128, 3), dim3(256), 0, stream,
                       idln_bf, Wb, qb, kb, vT);
    hipLaunchKernelGGL(attn_fused_kernel, dim3(1, S / 64, H * B), dim3(256), 0, stream,
                       qb, kb, vT, Aout, O);
    hipLaunchKernelGGL(final_kernel, dim3(M), dim3(256), 0, stream,
                       id, id_ln, O, g1, b1, g2, b2, out);
}

// Round 8
// 226.999 us; speedup vs baseline: 1.1796x; 1.0640x over previous
//
#include <hip/hip_runtime.h>

namespace {

constexpr int B = 2, S = 1024, D = 1024, H = 16, DH = 64;
constexpr int M = B * S;  // 2048 rows
constexpr float EPS = 1e-5f;

using bf16x8 = __attribute__((ext_vector_type(8))) short;  // MFMA A/B frag, K=32 (4 VGPRs)
using bf16x4 = __attribute__((ext_vector_type(4))) short;  // MFMA A/B frag, K=16 (2 VGPRs)
using f32x4  = __attribute__((ext_vector_type(4))) float;  // MFMA C/D frag

typedef const __attribute__((address_space(1))) void* gptr_t;
typedef __attribute__((address_space(3))) void* lptr_t;

__device__ __forceinline__ unsigned short f2bf(float f) {
    union { float f; unsigned u; } v{f};
    unsigned r = v.u + 0x7fffu + ((v.u >> 16) & 1u);  // RNE
    return (unsigned short)(r >> 16);
}

__device__ __forceinline__ float wave_sum(float v) {
#pragma unroll
    for (int off = 32; off > 0; off >>= 1) v += __shfl_down(v, off, 64);
    return v;
}

// ---------------- Kernel 0: W fp32 -> bf16 ----------------
__global__ __launch_bounds__(256) void cvt_w_kernel(
    const float* __restrict__ Wq, const float* __restrict__ Wk,
    const float* __restrict__ Wv, unsigned short* __restrict__ Wb)
{
    const float* src = (blockIdx.z == 0) ? Wq : (blockIdx.z == 1) ? Wk : Wv;
    const size_t i = ((size_t)blockIdx.x * 256 + threadIdx.x) * 4;
    float4 f = *reinterpret_cast<const float4*>(src + i);
    ushort4 h;
    h.x = f2bf(f.x); h.y = f2bf(f.y); h.z = f2bf(f.z); h.w = f2bf(f.w);
    *reinterpret_cast<ushort4*>(Wb + (size_t)blockIdx.z * D * D + i) = h;
}

// ---------------- Kernel 1: LN(id) -> id_ln (fp32 + bf16) ----------------
__global__ __launch_bounds__(256) void ln0_kernel(
    const float* __restrict__ x, const float* __restrict__ g,
    const float* __restrict__ bt, float* __restrict__ y,
    unsigned short* __restrict__ yb)
{
    __shared__ float sm[8];
    __shared__ float stats[2];
    const int row = blockIdx.x;
    const int t = threadIdx.x;
    const float4 v = reinterpret_cast<const float4*>(x + (size_t)row * D)[t];
    float s  = v.x + v.y + v.z + v.w;
    float ss = v.x*v.x + v.y*v.y + v.z*v.z + v.w*v.w;
    s = wave_sum(s); ss = wave_sum(ss);
    const int lane = t & 63, wid = t >> 6;
    if (lane == 0) { sm[wid] = s; sm[4 + wid] = ss; }
    __syncthreads();
    if (t == 0) {
        float S1 = sm[0] + sm[1] + sm[2] + sm[3];
        float S2 = sm[4] + sm[5] + sm[6] + sm[7];
        float m  = S1 * (1.0f / D);
        float var = S2 * (1.0f / D) - m * m;
        stats[0] = m; stats[1] = rsqrtf(var + EPS);
    }
    __syncthreads();
    const float m = stats[0], r = stats[1];
    const float4 gv = reinterpret_cast<const float4*>(g)[t];
    const float4 bv = reinterpret_cast<const float4*>(bt)[t];
    float4 o;
    o.x = (v.x - m) * r * gv.x + bv.x;
    o.y = (v.y - m) * r * gv.y + bv.y;
    o.z = (v.z - m) * r * gv.z + bv.z;
    o.w = (v.w - m) * r * gv.w + bv.w;
    reinterpret_cast<float4*>(y + (size_t)row * D)[t] = o;
    ushort4 h; h.x = f2bf(o.x); h.y = f2bf(o.y); h.z = f2bf(o.z); h.w = f2bf(o.w);
    *reinterpret_cast<ushort4*>(yb + (size_t)row * D + t * 4) = h;
}

// ---------------- Kernel 2: q/k/v = id_ln @ W^T, bf16 MFMA 128x128 ----------
// R0 structure + CORRECTLY-ORDERED 2-phase dbuf: per K-step,
//   ds_read frags(cur) -> sched_barrier -> STAGE(t+1 -> cur^1) -> MFMA -> barrier.
// Rationale: issuing global_load_lds BEFORE the ds_reads (R3) makes the
// compiler insert a vmcnt(0) wait before the reads (may-alias As[cur] vs
// As[cur^1]) -> full latency exposed; R3 measured +19us. With reads first,
// the prefetch drains at the barrier AFTER the MFMAs -> latency hidden.
__global__ __launch_bounds__(256) void qkv_mfma_kernel(
    const unsigned short* __restrict__ idln, const unsigned short* __restrict__ Wb,
    unsigned short* __restrict__ q, unsigned short* __restrict__ k,
    unsigned short* __restrict__ vT)
{
    __shared__ unsigned short As[2][128 * 32];
    __shared__ unsigned short Bs[2][128 * 32];
    const int zi = blockIdx.z;
    const unsigned short* Bmat = Wb + (size_t)zi * D * D;
    const int m0 = blockIdx.y * 128, n0 = blockIdx.x * 128;
    const int t = threadIdx.x;
    const int w = t >> 6, lane = t & 63;
    const int wm = (w >> 1) * 64, wn = (w & 1) * 64;
    const int quad = lane >> 4, l16 = lane & 15;
    const int srow = t >> 2;          // 0..63
    const int scol = (t & 3) * 8;     // 0,8,16,24 (bf16 elems)

    f32x4 acc[4][4];
#pragma unroll
    for (int i = 0; i < 4; ++i)
#pragma unroll
        for (int j = 0; j < 4; ++j) acc[i][j] = (f32x4){0.f, 0.f, 0.f, 0.f};

    auto STAGE = [&](int kk0, int bb) {
#pragma unroll
        for (int c = 0; c < 2; ++c) {
            const unsigned short* ga = idln + (size_t)(m0 + srow + c * 64) * D + kk0 + scol;
            __builtin_amdgcn_global_load_lds((gptr_t)ga, (lptr_t)(As[bb] + t * 8 + c * 2048), 16, 0, 0);
            const unsigned short* gb = Bmat + (size_t)(n0 + srow + c * 64) * D + kk0 + scol;
            __builtin_amdgcn_global_load_lds((gptr_t)gb, (lptr_t)(Bs[bb] + t * 8 + c * 2048), 16, 0, 0);
        }
    };

    STAGE(0, 0);
    __syncthreads();
    int cur = 0;
    for (int k0 = 0; k0 < D; k0 += 32) {
        // (1) fragment reads of current buffer FIRST
        bf16x8 af[4], bfr[4];
#pragma unroll
        for (int i = 0; i < 4; ++i)
            af[i] = *reinterpret_cast<const bf16x8*>(As[cur] + (wm + i * 16 + l16) * 32 + quad * 8);
#pragma unroll
        for (int j = 0; j < 4; ++j)
            bfr[j] = *reinterpret_cast<const bf16x8*>(Bs[cur] + (wn + j * 16 + l16) * 32 + quad * 8);
        __builtin_amdgcn_sched_barrier(0);   // pin: no gload_lds above the ds_reads
        // (2) prefetch next tile into the other buffer
        if (k0 + 32 < D) STAGE(k0 + 32, cur ^ 1);
        // (3) compute
#pragma unroll
        for (int i = 0; i < 4; ++i)
#pragma unroll
            for (int j = 0; j < 4; ++j)
                acc[i][j] = __builtin_amdgcn_mfma_f32_16x16x32_bf16(af[i], bfr[j], acc[i][j], 0, 0, 0);
        // (4) barrier drains the prefetch AFTER compute
        __syncthreads();
        cur ^= 1;
    }

    if (zi < 2) {
        unsigned short* C = (zi == 0) ? q : k;
#pragma unroll
        for (int i = 0; i < 4; ++i)
#pragma unroll
            for (int j = 0; j < 4; ++j) {
                const int gcol = n0 + wn + j * 16 + l16;
#pragma unroll
                for (int reg = 0; reg < 4; ++reg) {
                    const int grow = m0 + wm + i * 16 + quad * 4 + reg;
                    C[(size_t)grow * D + gcol] = f2bf(acc[i][j][reg]);
                }
            }
    } else {
        const int b = m0 >> 10;
#pragma unroll
        for (int i = 0; i < 4; ++i)
#pragma unroll
            for (int j = 0; j < 4; ++j) {
                const int gcol = n0 + wn + j * 16 + l16;          // flat D index = h*64+dh
                const int srow0 = (m0 - b * S) + wm + i * 16 + quad * 4;
                ushort4 h;
                h.x = f2bf(acc[i][j][0]); h.y = f2bf(acc[i][j][1]);
                h.z = f2bf(acc[i][j][2]); h.w = f2bf(acc[i][j][3]);
                *reinterpret_cast<ushort4*>(vT + ((size_t)b * D + gcol) * S + srow0) = h;
            }
    }
}

// ------- Kernel 3: two-pass fused attention (R0 base) + ordered 2-phase dbuf -------
// Grid: (1, S/64, H*B). Block 256 = 4 waves; wave w owns q-rows m0+w*16..+15.
// Same reads-first / prefetch-second / compute-third / barrier-fourth ordering
// in both passes. Fragment addressing byte-identical to R0.
__global__ __launch_bounds__(256) void attn_fused_kernel(
    const unsigned short* __restrict__ q, const unsigned short* __restrict__ k,
    const unsigned short* __restrict__ vT, float* __restrict__ Aout,
    float* __restrict__ O)
{
    __shared__ unsigned short Qs[2 * 64 * 32];       // [c][qrow][32dh]      8 KB
    __shared__ unsigned short Ks[2][2 * 64 * 32];    // dbuf [c][key][32dh] 16 KB
    __shared__ unsigned short Vs[2][4 * 64 * 16];    // dbuf [kt][dh][16k]  16 KB
    __shared__ float sInv[64];

    const int z = blockIdx.z;            // z = h*B + b (head-major A layout)
    const int b = z & 1, h = z >> 1;
    const int m0 = blockIdx.y * 64;
    const int t = threadIdx.x;
    const int w = t >> 6, lane = t & 63;
    const int quad = lane >> 4, l16 = lane & 15;
    const int sr = t >> 2, sc8 = (t & 3) * 8;

    auto STAGE_K = [&](int n0, int bb) {
#pragma unroll
        for (int c = 0; c < 2; ++c) {
            const unsigned short* gk = k + (size_t)(b * S + n0 + sr) * D + h * DH + c * 32 + sc8;
            __builtin_amdgcn_global_load_lds((gptr_t)gk, (lptr_t)(Ks[bb] + c * 2048 + t * 8), 16, 0, 0);
        }
    };
    auto STAGE_V = [&](int n0, int bb) {
#pragma unroll
        for (int c2 = 0; c2 < 2; ++c2) {
            const int kt = c2 * 2 + (t >> 7);
            const int dh = (t >> 1) & 63;
            const int kh = t & 1;
            const unsigned short* gv = vT + ((size_t)b * D + h * DH + dh) * S + n0 + kt * 16 + kh * 8;
            __builtin_amdgcn_global_load_lds((gptr_t)gv, (lptr_t)(Vs[bb] + c2 * 2048 + t * 8), 16, 0, 0);
        }
    };

    // stage Q tile (64 x 64) once + K tile 0
#pragma unroll
    for (int c = 0; c < 2; ++c) {
        const unsigned short* gq = q + (size_t)(b * S + m0 + sr) * D + h * DH + c * 32 + sc8;
        __builtin_amdgcn_global_load_lds((gptr_t)gq, (lptr_t)(Qs + c * 2048 + t * 8), 16, 0, 0);
    }
    STAGE_K(0, 0);
    __syncthreads();
    // hoist Q B-frags (q = w*16 + l16, dh = c*32 + quad*8..+7)
    bf16x8 qf[2];
#pragma unroll
    for (int c = 0; c < 2; ++c)
        qf[c] = *reinterpret_cast<const bf16x8*>(Qs + c * 2048 + (w * 16 + l16) * 32 + quad * 8);

    // ---------------- pass 1: row sums of exp(qk/8) ----------------
    float rsum = 0.f;
    int cur = 0;
    for (int tt = 0; tt < 16; ++tt) {
        // (1) read all K frags of current buffer
        bf16x8 kf[4][2];
#pragma unroll
        for (int kt = 0; kt < 4; ++kt)
#pragma unroll
            for (int c = 0; c < 2; ++c)
                kf[kt][c] = *reinterpret_cast<const bf16x8*>(Ks[cur] + c * 2048 + (kt * 16 + l16) * 32 + quad * 8);
        __builtin_amdgcn_sched_barrier(0);
        // (2) prefetch next K tile
        if (tt < 15) STAGE_K((tt + 1) * 64, cur ^ 1);
        // (3) compute
#pragma unroll
        for (int kt = 0; kt < 4; ++kt) {
            f32x4 a = (f32x4){0.f, 0.f, 0.f, 0.f};
#pragma unroll
            for (int c = 0; c < 2; ++c)
                a = __builtin_amdgcn_mfma_f32_16x16x32_bf16(kf[kt][c], qf[c], a, 0, 0, 0);
#pragma unroll
            for (int r = 0; r < 4; ++r) rsum += __expf(a[r] * 0.125f);
        }
        // (4) barrier
        __syncthreads();
        cur ^= 1;
    }
    // cur == 0 again. Stage pass-2 tile 0 while reducing the denominator.
    STAGE_K(0, 0);
    STAGE_V(0, 0);
    rsum += __shfl_xor(rsum, 16, 64);
    rsum += __shfl_xor(rsum, 32, 64);
    if (lane < 16) sInv[w * 16 + lane] = 1.0f / rsum;
    const float sL = 1.0f / rsum;   // every lane has the full sum for q-row l16

    f32x4 accO[4];
#pragma unroll
    for (int jj = 0; jj < 4; ++jj) accO[jj] = (f32x4){0.f, 0.f, 0.f, 0.f};
    float* Az = Aout + (size_t)z * S * S + (size_t)(m0 + w * 16 + l16) * S;
    __syncthreads();

    // ---------------- pass 2: recompute, write A (normalized), accumulate O ----
    cur = 0;
    for (int tt = 0; tt < 16; ++tt) {
        const int n0 = tt * 64;
        // (1) read all K and V frags of current buffers
        bf16x8 kf[4][2];
        bf16x4 vv[4][4];
#pragma unroll
        for (int kt = 0; kt < 4; ++kt) {
#pragma unroll
            for (int c = 0; c < 2; ++c)
                kf[kt][c] = *reinterpret_cast<const bf16x8*>(Ks[cur] + c * 2048 + (kt * 16 + l16) * 32 + quad * 8);
#pragma unroll
            for (int jj = 0; jj < 4; ++jj)
                vv[kt][jj] = *reinterpret_cast<const bf16x4*>(Vs[cur] + kt * 1024 + (jj * 16 + l16) * 16 + quad * 4);
        }
        __builtin_amdgcn_sched_barrier(0);
        // (2) prefetch next K+V tiles
        if (tt < 15) { STAGE_K(n0 + 64, cur ^ 1); STAGE_V(n0 + 64, cur ^ 1); }
        // (3) compute
#pragma unroll
        for (int kt = 0; kt < 4; ++kt) {
            f32x4 a = (f32x4){0.f, 0.f, 0.f, 0.f};
#pragma unroll
            for (int c = 0; c < 2; ++c)
                a = __builtin_amdgcn_mfma_f32_16x16x32_bf16(kf[kt][c], qf[c], a, 0, 0, 0);
            float e0 = __expf(a[0] * 0.125f) * sL;
            float e1 = __expf(a[1] * 0.125f) * sL;
            float e2 = __expf(a[2] * 0.125f) * sL;
            float e3 = __expf(a[3] * 0.125f) * sL;
            // write final A: lane's q-row, keys n0+kt*16+quad*4 .. +3 (16B store)
            *reinterpret_cast<float4*>(Az + n0 + kt * 16 + quad * 4) = make_float4(e0, e1, e2, e3);
            // pack P a-frag for x16 MFMA: A[m=q=l16][k=key=quad*4+j]
            bf16x4 p;
            p[0] = (short)f2bf(e0); p[1] = (short)f2bf(e1);
            p[2] = (short)f2bf(e2); p[3] = (short)f2bf(e3);
#pragma unroll
            for (int jj = 0; jj < 4; ++jj)
                accO[jj] = __builtin_amdgcn_mfma_f32_16x16x16bf16_1k(p, vv[kt][jj], accO[jj], 0, 0, 0);
        }
        // (4) barrier
        __syncthreads();
        cur ^= 1;
    }
    // write O: D row = q = quad*4+r (within wave's 16 rows), col dh = jj*16+l16
#pragma unroll
    for (int jj = 0; jj < 4; ++jj)
#pragma unroll
        for (int r = 0; r < 4; ++r) {
            const int grow = b * S + m0 + w * 16 + quad * 4 + r;
            O[(size_t)grow * D + h * DH + jj * 16 + l16] = accO[jj][r];
        }
}

// ---------------- Kernel 4: out = LN(id_ln+O,g1,b1) + LN(id+O,g2,b2) ----------
__global__ __launch_bounds__(256) void final_kernel(
    const float* __restrict__ id, const float* __restrict__ id_ln, const float* __restrict__ O,
    const float* __restrict__ g1, const float* __restrict__ b1,
    const float* __restrict__ g2, const float* __restrict__ b2,
    float* __restrict__ out)
{
    __shared__ float sm[16];
    __shared__ float stats[4];
    const int row = blockIdx.x;
    const int t = threadIdx.x;
    const size_t base = (size_t)row * D;
    const float4 xi = reinterpret_cast<const float4*>(id + base)[t];
    const float4 xl = reinterpret_cast<const float4*>(id_ln + base)[t];
    const float4 xo = reinterpret_cast<const float4*>(O + base)[t];
    float4 t1, t2;
    t1.x = xl.x + xo.x; t1.y = xl.y + xo.y; t1.z = xl.z + xo.z; t1.w = xl.w + xo.w;
    t2.x = xi.x + xo.x; t2.y = xi.y + xo.y; t2.z = xi.z + xo.z; t2.w = xi.w + xo.w;
    float s1  = t1.x + t1.y + t1.z + t1.w;
    float ss1 = t1.x*t1.x + t1.y*t1.y + t1.z*t1.z + t1.w*t1.w;
    float s2  = t2.x + t2.y + t2.z + t2.w;
    float ss2 = t2.x*t2.x + t2.y*t2.y + t2.z*t2.z + t2.w*t2.w;
    s1 = wave_sum(s1); ss1 = wave_sum(ss1);
    s2 = wave_sum(s2); ss2 = wave_sum(ss2);
    const int lane = t & 63, wid = t >> 6;
    if (lane == 0) { sm[wid] = s1; sm[4+wid] = ss1; sm[8+wid] = s2; sm[12+wid] = ss2; }
    __syncthreads();
    if (t == 0) {
        float S1 = sm[0]+sm[1]+sm[2]+sm[3];
        float Q1 = sm[4]+sm[5]+sm[6]+sm[7];
        float S2 = sm[8]+sm[9]+sm[10]+sm[11];
        float Q2 = sm[12]+sm[13]+sm[14]+sm[15];
        float m1 = S1 * (1.0f / D);
        float m2 = S2 * (1.0f / D);
        stats[0] = m1; stats[1] = rsqrtf(Q1 * (1.0f / D) - m1*m1 + EPS);
        stats[2] = m2; stats[3] = rsqrtf(Q2 * (1.0f / D) - m2*m2 + EPS);
    }
    __syncthreads();
    const float m1 = stats[0], r1 = stats[1], m2 = stats[2], r2 = stats[3];
    const float4 g1v = reinterpret_cast<const float4*>(g1)[t];
    const float4 b1v = reinterpret_cast<const float4*>(b1)[t];
    const float4 g2v = reinterpret_cast<const float4*>(g2)[t];
    const float4 b2v = reinterpret_cast<const float4*>(b2)[t];
    float4 o;
    o.x = (t1.x - m1)*r1*g1v.x + b1v.x + (t2.x - m2)*r2*g2v.x + b2v.x;
    o.y = (t1.y - m1)*r1*g1v.y + b1v.y + (t2.y - m2)*r2*g2v.y + b2v.y;
    o.z = (t1.z - m1)*r1*g1v.z + b1v.z + (t2.z - m2)*r2*g2v.z + b2v.z;
    o.w = (t1.w - m1)*r1*g1v.w + b1v.w + (t2.w - m2)*r2*g2v.w + b2v.w;
    reinterpret_cast<float4*>(out + base)[t] = o;
}

}  // namespace

extern "C" void kernel_launch(void* const* d_in, const int* in_sizes, int n_in,
                              void* d_out, int out_size, void* d_ws, size_t ws_size,
                              hipStream_t stream)
{
    const float* id = (const float*)d_in[0];
    const float* Wq = (const float*)d_in[1];
    const float* Wk = (const float*)d_in[2];
    const float* Wv = (const float*)d_in[3];
    const float* g0 = (const float*)d_in[4];
    const float* b0 = (const float*)d_in[5];
    const float* g1 = (const float*)d_in[6];
    const float* b1 = (const float*)d_in[7];
    const float* g2 = (const float*)d_in[8];
    const float* b2 = (const float*)d_in[9];

    float* out  = (float*)d_out;
    float* Aout = out + (size_t)B * S * D;   // A region [H*B, S, S], written once by attn

    char* ws = (char*)d_ws;
    float* id_ln  = (float*)(ws);                          //  8 MiB fp32
    float* O      = (float*)(ws + (8u << 20));             //  8 MiB fp32
    unsigned short* idln_bf = (unsigned short*)(ws + (16u << 20)); // 4 MiB
    unsigned short* Wb      = idln_bf + (size_t)M * D;     //  6 MiB (3 x DxD bf16)
    unsigned short* qb      = Wb + (size_t)3 * D * D;      //  4 MiB
    unsigned short* kb      = qb + (size_t)M * D;          //  4 MiB
    unsigned short* vT      = kb + (size_t)M * D;          //  4 MiB  [B][D][S]

    hipLaunchKernelGGL(cvt_w_kernel, dim3(D * D / 1024, 1, 3), dim3(256), 0, stream,
                       Wq, Wk, Wv, Wb);
    hipLaunchKernelGGL(ln0_kernel, dim3(M), dim3(256), 0, stream, id, g0, b0, id_ln, idln_bf);
    hipLaunchKernelGGL(qkv_mfma_kernel, dim3(D / 128, M / 128, 3), dim3(256), 0, stream,
                       idln_bf, Wb, qb, kb, vT);
    hipLaunchKernelGGL(attn_fused_kernel, dim3(1, S / 64, H * B), dim3(256), 0, stream,
                       qb, kb, vT, Aout, O);
    hipLaunchKernelGGL(final_kernel, dim3(M), dim3(256), 0, stream,
                       id, id_ln, O, g1, b1, g2, b2, out);
}